// Round 2
// baseline (1189.913 us; speedup 1.0000x reference)
//
#include <hip/hip_runtime.h>

// Problem dims (fixed by setup_inputs): x:(8,64,512,512) f32, flow:(8,2,512,512) f32
#define BB 8
#define CC 64
#define HH 512
#define WW 512
#define TH 8                        // output rows per block
#define RAD 8                       // staged jitter radius (P(|N(0,1)|>8) ~ 1e-15)
#define SRMAX (TH + 2 * RAD + 1)    // 25 staged rows max = 51.2 KB LDS
#define NT (HH / TH)                // 64 tiles per (b,c)
#define NXCD 8

typedef float f4 __attribute__((ext_vector_type(4)));

// Block = 256 threads = one channel x 8-row tile.
// Gather happens in LDS (bank = x%32 since 512%32==0 -> conflict-free for
// consecutive-lane x), eliminating the ~40 cache-line transactions per
// wave-gather that bound the previous version. Rare out-of-window taps
// (|fy|>8) fall back to global loads for exact reference semantics.
__global__ __launch_bounds__(256) void align2d_warp_kernel(
    const float* __restrict__ x,
    const float* __restrict__ flow,
    float* __restrict__ out)
{
    __shared__ float lds[SRMAX * WW];          // 51200 B -> 3 blocks/CU

    const int nwg = BB * CC * NT;              // 32768
    const int cpx = nwg / NXCD;                // 4096 (divisible -> bijective)
    // XCD swizzle: each XCD gets one batch b, tiles-inner for halo reuse in L2
    const int wg  = (blockIdx.x % NXCD) * cpx + blockIdx.x / NXCD;

    const int t = wg & (NT - 1);               // tile index (fastest)
    const int c = (wg >> 6) & (CC - 1);
    const int b = wg >> 12;

    const int h0   = t * TH;
    const int W_lo = max(0, h0 - RAD);
    const int W_hi = min(HH - 1, h0 + TH + RAD);   // inclusive
    const int SR   = W_hi - W_lo + 1;              // <= 25

    const float* xc = x + ((size_t)b * CC + c) * (HH * WW);

    // ---- stage rows [W_lo, W_hi]: contiguous in global -> coalesced f4 copy
    {
        const f4* src = (const f4*)(xc + (size_t)W_lo * WW);
        f4*       dst = (f4*)lds;
        const int n4 = SR * (WW / 4);              // <= 3200
        for (int i = threadIdx.x; i < n4; i += 256) dst[i] = src[i];
    }
    __syncthreads();

    const float* fpx = flow + ((size_t)b * 2 + 0) * (HH * WW);
    const float* fpy = flow + ((size_t)b * 2 + 1) * (HH * WW);
    float*       ob  = out + ((size_t)b * CC + c) * (HH * WW);

    #pragma unroll 4
    for (int i = 0; i < (TH * WW) / 256; ++i) {    // 16 iterations
        const int p   = i * 256 + threadIdx.x;
        const int hh  = h0 + (p >> 9);
        const int ww  = p & (WW - 1);
        const int pix = hh * WW + ww;

        const float fx = fpx[pix];
        const float fy = fpy[pix];

        // border-clamped bilinear coords (mirrors reference semantics)
        float px = fminf(fmaxf((float)ww + fx, 0.0f), (float)(WW - 1));
        float py = fminf(fmaxf((float)hh + fy, 0.0f), (float)(HH - 1));
        float x0f = floorf(px);
        float y0f = floorf(py);
        float wx = px - x0f;
        float wy = py - y0f;
        int x0 = (int)x0f;
        int y0 = (int)y0f;
        int x1 = min(x0 + 1, WW - 1);
        int y1 = min(y0 + 1, HH - 1);

        float v00, v01, v10, v11;
        if (y0 >= W_lo && y1 <= W_hi) {
            const int r0 = (y0 - W_lo) * WW;
            const int r1 = (y1 - W_lo) * WW;
            v00 = lds[r0 + x0]; v01 = lds[r0 + x1];
            v10 = lds[r1 + x0]; v11 = lds[r1 + x1];
        } else {
            // astronomically rare (|fy| > 8), kept for exact correctness
            v00 = xc[y0 * WW + x0]; v01 = xc[y0 * WW + x1];
            v10 = xc[y1 * WW + x0]; v11 = xc[y1 * WW + x1];
        }

        const float w00 = (1.0f - wx) * (1.0f - wy);
        const float w01 = wx * (1.0f - wy);
        const float w10 = (1.0f - wx) * wy;
        const float w11 = wx * wy;
        float v = v00 * w00 + v01 * w01 + v10 * w10 + v11 * w11;

        // keep the 537 MB store stream out of L2/L3 so x window lines survive
        __builtin_nontemporal_store(v, ob + pix);
    }
}

// pass-through copy of flow into the tail of d_out (16 MiB, float4, nontemporal)
__global__ __launch_bounds__(256) void align2d_flowcopy_kernel(
    const f4* __restrict__ flow, f4* __restrict__ out)
{
    const int i = blockIdx.x * blockDim.x + threadIdx.x;
    f4 v = __builtin_nontemporal_load(flow + i);
    __builtin_nontemporal_store(v, out + i);
}

extern "C" void kernel_launch(void* const* d_in, const int* in_sizes, int n_in,
                              void* d_out, int out_size, void* d_ws, size_t ws_size,
                              hipStream_t stream) {
    const float* x    = (const float*)d_in[0];
    const float* flow = (const float*)d_in[1];
    float* out = (float*)d_out;

    const int nwg = BB * CC * NT;                  // 32768 blocks
    align2d_warp_kernel<<<nwg, 256, 0, stream>>>(x, flow, out);

    const int nflow4 = (BB * 2 * HH * WW) / 4;     // 1,048,576 float4
    float* out_flow = out + (size_t)BB * CC * HH * WW;
    align2d_flowcopy_kernel<<<nflow4 / 256, 256, 0, stream>>>(
        (const f4*)flow, (f4*)out_flow);
}